// Round 4
// baseline (1367.987 us; speedup 1.0000x reference)
//
#include <hip/hip_runtime.h>
#include <math.h>
#include <limits.h>

#define HH 1280
#define WW 1920
#define OUT_H 427
#define OUT_W 640
#define SENT 0x7fffffff

// ---------------- shared JFA helpers (bit-exact semantics) ----------------
__device__ __forceinline__ int d2f(int pi, int pj, int s) {
    int dr = pi - (s >> 11);
    int dc = pj - (s & 2047);
    return dr * dr + dc * dc;
}
// sequential semantics: take cand iff cand!=SENT and d(cand) < d(cur), strict
__device__ __forceinline__ int pick(int pi, int pj, int cur, int cand) {
    if (cand != SENT) {
        int dn = d2f(pi, pj, cand);
        int dc_ = (cur == SENT) ? INT_MAX : d2f(pi, pj, cur);
        if (dn < dc_) return cand;
    }
    return cur;
}
__device__ __forceinline__ int ldsc(const int* __restrict__ im, int r, int c) {
    return (r >= 0 && r < HH && c >= 0 && c < WW) ? im[(long)r * WW + c] : SENT;
}
__device__ __forceinline__ int4 ld4(const int* __restrict__ im, int r, int c) {
    int4 v;
    if (r < 0 || r >= HH) { v.x = v.y = v.z = v.w = SENT; return v; }
    if (c >= 0 && c + 3 < WW) {
        v = *reinterpret_cast<const int4*>(im + (long)r * WW + c);
    } else {
        v.x = ldsc(im, r, c);     v.y = ldsc(im, r, c + 1);
        v.z = ldsc(im, r, c + 2); v.w = ldsc(im, r, c + 3);
    }
    return v;
}

// ---------------- scatter: project points, atomicAdd depth ----------------
// Reproduces XLA CPU dot lowering bit-exactly: plain mul/add (no FMA),
// ascending-k accumulation, translation added after.
__global__ void scatter_k(const float* __restrict__ pts,
                          const float* __restrict__ pose,
                          const float* __restrict__ extr,
                          const float* __restrict__ intr,
                          float* __restrict__ depth, int N) {
    #pragma clang fp contract(off)
    int t = blockIdx.x * blockDim.x + threadIdx.x;
    int b = blockIdx.y;
    if (t >= N) return;
    const float* p = pts + ((long)b * N + t) * 3;
    float x = p[0], y = p[1], z = p[2];
    const float* P = pose + b * 16;
    const float* E = extr + b * 16;
    const float* K = intr + b * 9;
    float wx = ((x*P[0] + y*P[1]) + z*P[2]) + P[3];
    float wy = ((x*P[4] + y*P[5]) + z*P[6]) + P[7];
    float wz = ((x*P[8] + y*P[9]) + z*P[10]) + P[11];
    float cx = ((wx*E[0] + wy*E[1]) + wz*E[2]) + E[3];
    float cy = ((wx*E[4] + wy*E[5]) + wz*E[6]) + E[7];
    float cz = ((wx*E[8] + wy*E[9]) + wz*E[10]) + E[11];
    float px = (cx*K[0] + cy*K[1]) + cz*K[2];
    float py = (cx*K[3] + cy*K[4]) + cz*K[5];
    float pz = (cx*K[6] + cy*K[7]) + cz*K[8];
    float u = px / pz, v = py / pz;
    int r = (int)floorf(v), c = (int)floorf(u);
    if (r >= 0 && r < HH && c >= 0 && c < WW) {
        float dv = sqrtf((x*x + y*y) + z*z);
        atomicAdd(depth + ((long)b * HH + r) * WW + c, dv);
    }
}

// ------- fused: init (valid->self, else SENT) + step k=1 (8 passes) in LDS -------
#define TSA 64
#define HALA 3
#define RA (TSA + 2*HALA)   // 70
__global__ __launch_bounds__(256)
void init_jfa1_k(const float* __restrict__ depth, int* __restrict__ out) {
    __shared__ int buf0[RA * RA];
    __shared__ int buf1[RA * RA];
    int b = blockIdx.z;
    int gi0 = blockIdx.y * TSA - HALA;
    int gj0 = blockIdx.x * TSA - HALA;
    const float* dep = depth + (long)b * HH * WW;
    int tid = threadIdx.x;
    for (int idx = tid; idx < RA * RA; idx += 256) {
        int li = idx / RA, lj = idx % RA;
        int gi = gi0 + li, gj = gj0 + lj;
        int v = SENT;
        if (gi >= 0 && gi < HH && gj >= 0 && gj < WW)
            if (dep[(long)gi * WW + gj] != 0.0f) v = (gi << 11) | gj;
        buf0[idx] = v;
    }
    __syncthreads();
    int* src = buf0; int* dst = buf1;
    const int dys[8] = {-1,-1,-1, 0, 0, 1, 1, 1};
    const int dxs[8] = {-1, 0, 1,-1, 1,-1, 0, 1};
    #pragma unroll
    for (int pi = 0; pi < 8; ++pi) {
        int dy = dys[pi], dx = dxs[pi];
        for (int idx = tid; idx < RA * RA; idx += 256) {
            int li = idx / RA, lj = idx % RA;
            int gi = gi0 + li, gj = gj0 + lj;
            int v = SENT;
            if (gi >= 0 && gi < HH && gj >= 0 && gj < WW) {
                int c = src[idx];
                int ci = li - dy, cj = lj - dx;
                int cgi = gi - dy, cgj = gj - dx;
                int cand = SENT;
                if (cgi >= 0 && cgi < HH && cgj >= 0 && cgj < WW &&
                    ci >= 0 && ci < RA && cj >= 0 && cj < RA)
                    cand = src[ci * RA + cj];
                v = pick(gi, gj, c, cand);
            }
            dst[idx] = v;
        }
        __syncthreads();
        int* tswap = src; src = dst; dst = tswap;
    }
    int* op = out + (long)b * HH * WW;
    for (int idx = tid; idx < TSA * TSA; idx += 256) {
        int li = idx / TSA + HALA, lj = idx % TSA + HALA;
        int gi = gi0 + li, gj = gj0 + lj;   // tiles divide exactly: in-bounds
        op[(long)gi * WW + gj] = src[li * RA + lj];
    }
}

// ------- fused tail: steps {4,2,1} (24 passes) in LDS, trapezoid-exact -------
#define TSB 64
#define HALB 21
#define RB (TSB + 2*HALB)   // 106
__global__ __launch_bounds__(512)
void jfa_tail_k(const int* __restrict__ in, int* __restrict__ out) {
    __shared__ int buf0[RB * RB];
    __shared__ int buf1[RB * RB];
    int b = blockIdx.z;
    int gi0 = blockIdx.y * TSB - HALB;
    int gj0 = blockIdx.x * TSB - HALB;
    const int* im = in + (long)b * HH * WW;
    int tid = threadIdx.x;
    for (int idx = tid; idx < RB * RB; idx += 512) {
        int li = idx / RB, lj = idx % RB;
        buf0[idx] = ldsc(im, gi0 + li, gj0 + lj);
    }
    __syncthreads();
    int* src = buf0; int* dst = buf1;
    const int ksl[3] = {4, 2, 1};
    const int dys[8] = {-1,-1,-1, 0, 0, 1, 1, 1};
    const int dxs[8] = {-1, 0, 1,-1, 1,-1, 0, 1};
    for (int s = 0; s < 3; ++s) {
        int k = ksl[s];
        for (int pi = 0; pi < 8; ++pi) {
            int dy = dys[pi] * k, dx = dxs[pi] * k;
            for (int idx = tid; idx < RB * RB; idx += 512) {
                int li = idx / RB, lj = idx % RB;
                int gi = gi0 + li, gj = gj0 + lj;
                int v = SENT;
                if (gi >= 0 && gi < HH && gj >= 0 && gj < WW) {
                    int c = src[idx];
                    int ci = li - dy, cj = lj - dx;
                    int cgi = gi - dy, cgj = gj - dx;
                    int cand = SENT;
                    if (cgi >= 0 && cgi < HH && cgj >= 0 && cgj < WW &&
                        ci >= 0 && ci < RB && cj >= 0 && cj < RB)
                        cand = src[ci * RB + cj];
                    v = pick(gi, gj, c, cand);
                }
                dst[idx] = v;
            }
            __syncthreads();
            int* tswap = src; src = dst; dst = tswap;
        }
    }
    int* op = out + (long)b * HH * WW;
    for (int idx = tid; idx < TSB * TSB; idx += 512) {
        int li = idx / TSB + HALB, lj = idx % TSB + HALB;
        int gi = gi0 + li, gj = gj0 + lj;
        op[(long)gi * WW + gj] = src[li * RB + lj];
    }
}

// ---- fused group of 3 passes, fixed dy: (dy,-k),(dy,0),(dy,+k); 4 px/thread ----
__global__ __launch_bounds__(256)
void jfa3_k(const int* __restrict__ in, int* __restrict__ out, int dy, int k) {
    int jt = blockIdx.x * blockDim.x + threadIdx.x;
    if (jt >= WW / 4) return;
    int j0 = jt * 4;
    int i = blockIdx.y, b = blockIdx.z;
    const int* im = in + (long)b * HH * WW;
    int4 v_r0_0  = ld4(im, i,          j0);
    int4 v_r1_pk = ld4(im, i - dy,     j0 + k);
    int4 v_r1_0  = ld4(im, i - dy,     j0);
    int4 v_r1_mk = ld4(im, i - dy,     j0 - k);
    int4 v_r2_pk = ld4(im, i - 2*dy,   j0 + k);
    int4 v_r2_0  = ld4(im, i - 2*dy,   j0);
    int4 v_r2_mk = ld4(im, i - 2*dy,   j0 - k);
    int4 v_r3_0  = ld4(im, i - 3*dy,   j0);
    int r0_0[4]  = {v_r0_0.x,  v_r0_0.y,  v_r0_0.z,  v_r0_0.w};
    int r1_pk[4] = {v_r1_pk.x, v_r1_pk.y, v_r1_pk.z, v_r1_pk.w};
    int r1_0[4]  = {v_r1_0.x,  v_r1_0.y,  v_r1_0.z,  v_r1_0.w};
    int r1_mk[4] = {v_r1_mk.x, v_r1_mk.y, v_r1_mk.z, v_r1_mk.w};
    int r2_pk[4] = {v_r2_pk.x, v_r2_pk.y, v_r2_pk.z, v_r2_pk.w};
    int r2_0[4]  = {v_r2_0.x,  v_r2_0.y,  v_r2_0.z,  v_r2_0.w};
    int r2_mk[4] = {v_r2_mk.x, v_r2_mk.y, v_r2_mk.z, v_r2_mk.w};
    int r3_0[4]  = {v_r3_0.x,  v_r3_0.y,  v_r3_0.z,  v_r3_0.w};
    int res[4];
    #pragma unroll
    for (int t = 0; t < 4; ++t) {
        int j = j0 + t;
        // pass1 at p:            out1[p]  = pick_p(in[p], in[i-dy, j+k])
        int o1_p = pick(i, j, r0_0[t], r1_pk[t]);
        // out1 at (i-dy, j):     pick there of in[i-dy,j], in[i-2dy, j+k]
        int o1_m = (i - dy >= 0 && i - dy < HH)
                 ? pick(i - dy, j, r1_0[t], r2_pk[t]) : SENT;
        int o2_p = pick(i, j, o1_p, o1_m);
        // out2 at q=(i-dy, j-k)
        int o2_q;
        int qi = i - dy, qj = j - k;
        if (qi < 0 || qi >= HH || qj < 0 || qj >= WW) o2_q = SENT;
        else {
            int a0 = pick(qi, qj, r1_mk[t], r2_0[t]);
            int a1 = (qi - dy >= 0 && qi - dy < HH)
                   ? pick(qi - dy, qj, r2_mk[t], r3_0[t]) : SENT;
            o2_q = pick(qi, qj, a0, a1);
        }
        res[t] = pick(i, j, o2_p, o2_q);
    }
    int4 ov; ov.x = res[0]; ov.y = res[1]; ov.z = res[2]; ov.w = res[3];
    *reinterpret_cast<int4*>(out + (long)b * HH * WW + (long)i * WW + j0) = ov;
}

// ---- fused group of 2 passes, dy=0: (0,-k),(0,+k); 4 px/thread ----
__global__ __launch_bounds__(256)
void jfa2_k(const int* __restrict__ in, int* __restrict__ out, int k) {
    int jt = blockIdx.x * blockDim.x + threadIdx.x;
    if (jt >= WW / 4) return;
    int j0 = jt * 4;
    int i = blockIdx.y, b = blockIdx.z;
    const int* im = in + (long)b * HH * WW;
    int4 vv0  = ld4(im, i, j0);
    int4 vvpk = ld4(im, i, j0 + k);
    int4 vvmk = ld4(im, i, j0 - k);
    int a0[4] = {vv0.x,  vv0.y,  vv0.z,  vv0.w};
    int apk[4] = {vvpk.x, vvpk.y, vvpk.z, vvpk.w};
    int amk[4] = {vvmk.x, vvmk.y, vvmk.z, vvmk.w};
    int res[4];
    #pragma unroll
    for (int t = 0; t < 4; ++t) {
        int j = j0 + t;
        int o1_p = pick(i, j, a0[t], apk[t]);
        int o1_m = (j - k >= 0) ? pick(i, j - k, amk[t], a0[t]) : SENT;
        res[t] = pick(i, j, o1_p, o1_m);
    }
    int4 ov; ov.x = res[0]; ov.y = res[1]; ov.z = res[2]; ov.w = res[3];
    *reinterpret_cast<int4*>(out + (long)b * HH * WW + (long)i * WW + j0) = ov;
}

// ------- compose filled/dist on the fly + horizontal resize (W 1920->640) -------
__global__ void hresize_k(const float* __restrict__ depth,
                          const int* __restrict__ nr,
                          float* __restrict__ tmp) {
    int ow = blockIdx.x * blockDim.x + threadIdx.x;
    int i = blockIdx.y, b = blockIdx.z;
    if (ow >= OUT_W) return;
    const float inv = 3.0f;  // 1920/640
    float sf = (ow + 0.5f) * inv - 0.5f;
    int i0 = (int)ceilf(sf - inv);
    float a0 = 0.f, a1 = 0.f, wsum = 0.f;
    long rowbase = ((long)b * HH + i) * WW;
    long imgbase = (long)b * HH * WW;
    for (int k = 0; k < 7; ++k) {
        int iw = i0 + k;
        if (iw < 0 || iw >= WW) continue;
        float wgt = 1.0f - fabsf(sf - (float)iw) / inv;
        if (wgt <= 0.0f) continue;
        float dv = depth[rowbase + iw];
        float f, dist;
        if (dv != 0.0f) { f = dv; dist = 0.0f; }
        else {
            int nn = nr[rowbase + iw];
            int rr, cc;
            if (nn == SENT) { rr = HH - 1; cc = WW - 1; }  // clip(BIG) path
            else { rr = nn >> 11; cc = nn & 2047; }
            f = depth[imgbase + (long)rr * WW + cc];
            float drr = (float)i - (float)rr, dcc = (float)iw - (float)cc;
            dist = sqrtf(drr * drr + dcc * dcc);
        }
        a0 += wgt * f; a1 += wgt * dist; wsum += wgt;
    }
    long o = (((long)b * 2 + 0) * HH + i) * OUT_W + ow;
    tmp[o] = a0 / wsum;
    tmp[o + (long)HH * OUT_W] = a1 / wsum;
}

// ---------------- vertical resize (H 1280->427) ----------------
__global__ void vresize_k(const float* __restrict__ tmp, float* __restrict__ out) {
    int ow = blockIdx.x * blockDim.x + threadIdx.x;
    int oh = blockIdx.y, bc = blockIdx.z;  // bc = b*2 + ch
    if (ow >= OUT_W) return;
    const float inv = (float)(1280.0 / 427.0);
    float sf = (oh + 0.5f) * inv - 0.5f;
    int i0 = (int)ceilf(sf - inv);
    float acc = 0.f, wsum = 0.f;
    const float* src = tmp + (long)bc * HH * OUT_W;
    for (int k = 0; k < 7; ++k) {
        int ih = i0 + k;
        if (ih < 0 || ih >= HH) continue;
        float wgt = 1.0f - fabsf(sf - (float)ih) / inv;
        if (wgt <= 0.0f) continue;
        acc += wgt * src[(long)ih * OUT_W + ow];
        wsum += wgt;
    }
    out[((long)bc * OUT_H + oh) * OUT_W + ow] = acc / wsum;
}

extern "C" void kernel_launch(void* const* d_in, const int* in_sizes, int n_in,
                              void* d_out, int out_size, void* d_ws, size_t ws_size,
                              hipStream_t stream) {
    const float* pts  = (const float*)d_in[0];
    const float* pose = (const float*)d_in[1];
    const float* extr = (const float*)d_in[2];
    const float* intr = (const float*)d_in[3];
    int B = in_sizes[1] / 16;
    int N = in_sizes[0] / (3 * B);

    char* ws = (char*)d_ws;
    size_t imgSz = (size_t)B * HH * WW;
    float* depth = (float*)ws;                  // B*H*W f32
    int*   nearA = (int*)(ws + imgSz * 4);      // B*H*W i32
    int*   nearB = (int*)(ws + imgSz * 8);      // B*H*W i32
    float* tmp   = (float*)(ws + imgSz * 12);   // B*2*H*OUT_W f32

    hipMemsetAsync(depth, 0, imgSz * sizeof(float), stream);

    dim3 bs(256);
    scatter_k<<<dim3((N + 255) / 256, B), bs, 0, stream>>>(pts, pose, extr, intr, depth, N);

    // step k=1 (first in schedule) fused with init, in LDS
    init_jfa1_k<<<dim3(WW / TSA, HH / TSA, B), 256, 0, stream>>>(depth, nearA);

    // steps 1024..8 via vectorized fused groups
    dim3 gv((WW / 4 + 255) / 256, HH, B);
    const int steps_big[8] = {1024, 512, 256, 128, 64, 32, 16, 8};
    int* cur = nearA; int* nxt = nearB;
    for (int s = 0; s < 8; ++s) {
        int k = steps_big[s];
        jfa3_k<<<gv, bs, 0, stream>>>(cur, nxt, -k, k);
        { int* t2 = cur; cur = nxt; nxt = t2; }
        jfa2_k<<<gv, bs, 0, stream>>>(cur, nxt, k);
        { int* t2 = cur; cur = nxt; nxt = t2; }
        jfa3_k<<<gv, bs, 0, stream>>>(cur, nxt, +k, k);
        { int* t2 = cur; cur = nxt; nxt = t2; }
    }

    // steps {4,2,1} fused in LDS (trapezoid-exact)
    jfa_tail_k<<<dim3(WW / TSB, HH / TSB, B), 512, 0, stream>>>(cur, nxt);
    { int* t2 = cur; cur = nxt; nxt = t2; }

    hresize_k<<<dim3((OUT_W + 255) / 256, HH, B), bs, 0, stream>>>(depth, cur, tmp);
    vresize_k<<<dim3((OUT_W + 255) / 256, OUT_H, B * 2), bs, 0, stream>>>(tmp, (float*)d_out);
}

// Round 5
// 801.904 us; speedup vs baseline: 1.7059x; 1.7059x over previous
//
#include <hip/hip_runtime.h>
#include <math.h>
#include <limits.h>

#define HH 1280
#define WW 1920
#define OUT_H 427
#define OUT_W 640
#define SENT 0x7fffffff

// ---------------- shared JFA helpers (bit-exact semantics) ----------------
__device__ __forceinline__ int d2f(int pi, int pj, int s) {
    int dr = pi - (s >> 11);
    int dc = pj - (s & 2047);
    return dr * dr + dc * dc;
}
// sequential semantics: take cand iff cand!=SENT and d(cand) < d(cur), strict
__device__ __forceinline__ int pick(int pi, int pj, int cur, int cand) {
    if (cand != SENT) {
        int dn = d2f(pi, pj, cand);
        int dc_ = (cur == SENT) ? INT_MAX : d2f(pi, pj, cur);
        if (dn < dc_) return cand;
    }
    return cur;
}
__device__ __forceinline__ int ldsc(const int* __restrict__ im, int r, int c) {
    return (r >= 0 && r < HH && c >= 0 && c < WW) ? im[(long)r * WW + c] : SENT;
}
// alignment-robust 4-wide load (k=1,2 shifts are not 16B-aligned)
__device__ __forceinline__ int4 ld4(const int* __restrict__ im, int r, int c) {
    int4 v;
    if (r < 0 || r >= HH) { v.x = v.y = v.z = v.w = SENT; return v; }
    if ((c & 3) == 0 && c >= 0 && c + 3 < WW) {
        v = *reinterpret_cast<const int4*>(im + (long)r * WW + c);
    } else {
        v.x = ldsc(im, r, c);     v.y = ldsc(im, r, c + 1);
        v.z = ldsc(im, r, c + 2); v.w = ldsc(im, r, c + 3);
    }
    return v;
}

// ---------------- scatter: project points, atomicAdd depth ----------------
// Reproduces XLA CPU dot lowering bit-exactly: plain mul/add (no FMA),
// ascending-k accumulation, translation added after.
__global__ void scatter_k(const float* __restrict__ pts,
                          const float* __restrict__ pose,
                          const float* __restrict__ extr,
                          const float* __restrict__ intr,
                          float* __restrict__ depth, int N) {
    #pragma clang fp contract(off)
    int t = blockIdx.x * blockDim.x + threadIdx.x;
    int b = blockIdx.y;
    if (t >= N) return;
    const float* p = pts + ((long)b * N + t) * 3;
    float x = p[0], y = p[1], z = p[2];
    const float* P = pose + b * 16;
    const float* E = extr + b * 16;
    const float* K = intr + b * 9;
    float wx = ((x*P[0] + y*P[1]) + z*P[2]) + P[3];
    float wy = ((x*P[4] + y*P[5]) + z*P[6]) + P[7];
    float wz = ((x*P[8] + y*P[9]) + z*P[10]) + P[11];
    float cx = ((wx*E[0] + wy*E[1]) + wz*E[2]) + E[3];
    float cy = ((wx*E[4] + wy*E[5]) + wz*E[6]) + E[7];
    float cz = ((wx*E[8] + wy*E[9]) + wz*E[10]) + E[11];
    float px = (cx*K[0] + cy*K[1]) + cz*K[2];
    float py = (cx*K[3] + cy*K[4]) + cz*K[5];
    float pz = (cx*K[6] + cy*K[7]) + cz*K[8];
    float u = px / pz, v = py / pz;
    int r = (int)floorf(v), c = (int)floorf(u);
    if (r >= 0 && r < HH && c >= 0 && c < WW) {
        float dv = sqrtf((x*x + y*y) + z*z);
        atomicAdd(depth + ((long)b * HH + r) * WW + c, dv);
    }
}

// ------- fused: init (valid->self, else SENT) + step k=1 (8 passes) in LDS -------
#define TSA 64
#define HALA 3
#define RA (TSA + 2*HALA)   // 70
__global__ __launch_bounds__(256)
void init_jfa1_k(const float* __restrict__ depth, int* __restrict__ out) {
    __shared__ int buf0[RA * RA];
    __shared__ int buf1[RA * RA];
    int b = blockIdx.z;
    int gi0 = blockIdx.y * TSA - HALA;
    int gj0 = blockIdx.x * TSA - HALA;
    const float* dep = depth + (long)b * HH * WW;
    int tid = threadIdx.x;
    for (int idx = tid; idx < RA * RA; idx += 256) {
        int li = idx / RA, lj = idx % RA;
        int gi = gi0 + li, gj = gj0 + lj;
        int v = SENT;
        if (gi >= 0 && gi < HH && gj >= 0 && gj < WW)
            if (dep[(long)gi * WW + gj] != 0.0f) v = (gi << 11) | gj;
        buf0[idx] = v;
    }
    __syncthreads();
    int* src = buf0; int* dst = buf1;
    const int dys[8] = {-1,-1,-1, 0, 0, 1, 1, 1};
    const int dxs[8] = {-1, 0, 1,-1, 1,-1, 0, 1};
    #pragma unroll
    for (int pi = 0; pi < 8; ++pi) {
        int dy = dys[pi], dx = dxs[pi];
        for (int idx = tid; idx < RA * RA; idx += 256) {
            int li = idx / RA, lj = idx % RA;
            int gi = gi0 + li, gj = gj0 + lj;
            int v = SENT;
            if (gi >= 0 && gi < HH && gj >= 0 && gj < WW) {
                int c = src[idx];
                int ci = li - dy, cj = lj - dx;
                int cgi = gi - dy, cgj = gj - dx;
                int cand = SENT;
                if (cgi >= 0 && cgi < HH && cgj >= 0 && cgj < WW &&
                    ci >= 0 && ci < RA && cj >= 0 && cj < RA)
                    cand = src[ci * RA + cj];
                v = pick(gi, gj, c, cand);
            }
            dst[idx] = v;
        }
        __syncthreads();
        int* tswap = src; src = dst; dst = tswap;
    }
    int* op = out + (long)b * HH * WW;
    for (int idx = tid; idx < TSA * TSA; idx += 256) {
        int li = idx / TSA + HALA, lj = idx % TSA + HALA;
        int gi = gi0 + li, gj = gj0 + lj;   // tiles divide exactly: in-bounds
        op[(long)gi * WW + gj] = src[li * RA + lj];
    }
}

// ---- fused group of 3 passes, fixed dy: (dy,-k),(dy,0),(dy,+k); 4 px/thread ----
__global__ __launch_bounds__(256)
void jfa3_k(const int* __restrict__ in, int* __restrict__ out, int dy, int k) {
    int jt = blockIdx.x * blockDim.x + threadIdx.x;
    if (jt >= WW / 4) return;
    int j0 = jt * 4;
    int i = blockIdx.y, b = blockIdx.z;
    const int* im = in + (long)b * HH * WW;
    int4 v_r0_0  = ld4(im, i,          j0);
    int4 v_r1_pk = ld4(im, i - dy,     j0 + k);
    int4 v_r1_0  = ld4(im, i - dy,     j0);
    int4 v_r1_mk = ld4(im, i - dy,     j0 - k);
    int4 v_r2_pk = ld4(im, i - 2*dy,   j0 + k);
    int4 v_r2_0  = ld4(im, i - 2*dy,   j0);
    int4 v_r2_mk = ld4(im, i - 2*dy,   j0 - k);
    int4 v_r3_0  = ld4(im, i - 3*dy,   j0);
    int r0_0[4]  = {v_r0_0.x,  v_r0_0.y,  v_r0_0.z,  v_r0_0.w};
    int r1_pk[4] = {v_r1_pk.x, v_r1_pk.y, v_r1_pk.z, v_r1_pk.w};
    int r1_0[4]  = {v_r1_0.x,  v_r1_0.y,  v_r1_0.z,  v_r1_0.w};
    int r1_mk[4] = {v_r1_mk.x, v_r1_mk.y, v_r1_mk.z, v_r1_mk.w};
    int r2_pk[4] = {v_r2_pk.x, v_r2_pk.y, v_r2_pk.z, v_r2_pk.w};
    int r2_0[4]  = {v_r2_0.x,  v_r2_0.y,  v_r2_0.z,  v_r2_0.w};
    int r2_mk[4] = {v_r2_mk.x, v_r2_mk.y, v_r2_mk.z, v_r2_mk.w};
    int r3_0[4]  = {v_r3_0.x,  v_r3_0.y,  v_r3_0.z,  v_r3_0.w};
    int res[4];
    #pragma unroll
    for (int t = 0; t < 4; ++t) {
        int j = j0 + t;
        int o1_p = pick(i, j, r0_0[t], r1_pk[t]);
        int o1_m = (i - dy >= 0 && i - dy < HH)
                 ? pick(i - dy, j, r1_0[t], r2_pk[t]) : SENT;
        int o2_p = pick(i, j, o1_p, o1_m);
        int o2_q;
        int qi = i - dy, qj = j - k;
        if (qi < 0 || qi >= HH || qj < 0 || qj >= WW) o2_q = SENT;
        else {
            int a0 = pick(qi, qj, r1_mk[t], r2_0[t]);
            int a1 = (qi - dy >= 0 && qi - dy < HH)
                   ? pick(qi - dy, qj, r2_mk[t], r3_0[t]) : SENT;
            o2_q = pick(qi, qj, a0, a1);
        }
        res[t] = pick(i, j, o2_p, o2_q);
    }
    int4 ov; ov.x = res[0]; ov.y = res[1]; ov.z = res[2]; ov.w = res[3];
    *reinterpret_cast<int4*>(out + (long)b * HH * WW + (long)i * WW + j0) = ov;
}

// ---- fused group of 2 passes, dy=0: (0,-k),(0,+k); 4 px/thread ----
__global__ __launch_bounds__(256)
void jfa2_k(const int* __restrict__ in, int* __restrict__ out, int k) {
    int jt = blockIdx.x * blockDim.x + threadIdx.x;
    if (jt >= WW / 4) return;
    int j0 = jt * 4;
    int i = blockIdx.y, b = blockIdx.z;
    const int* im = in + (long)b * HH * WW;
    int4 vv0  = ld4(im, i, j0);
    int4 vvpk = ld4(im, i, j0 + k);
    int4 vvmk = ld4(im, i, j0 - k);
    int a0[4] = {vv0.x,  vv0.y,  vv0.z,  vv0.w};
    int apk[4] = {vvpk.x, vvpk.y, vvpk.z, vvpk.w};
    int amk[4] = {vvmk.x, vvmk.y, vvmk.z, vvmk.w};
    int res[4];
    #pragma unroll
    for (int t = 0; t < 4; ++t) {
        int j = j0 + t;
        int o1_p = pick(i, j, a0[t], apk[t]);
        int o1_m = (j - k >= 0) ? pick(i, j - k, amk[t], a0[t]) : SENT;
        res[t] = pick(i, j, o1_p, o1_m);
    }
    int4 ov; ov.x = res[0]; ov.y = res[1]; ov.z = res[2]; ov.w = res[3];
    *reinterpret_cast<int4*>(out + (long)b * HH * WW + (long)i * WW + j0) = ov;
}

// ------- fused compose + horizontal resize: one block per image row -------
// Phase 1: compute (filled, dist) once per input pixel into LDS (gather once).
// Phase 2: 5-tap horizontal reduction from LDS (same op order as reference).
__global__ __launch_bounds__(256)
void hresize_k(const float* __restrict__ depth,
               const int* __restrict__ nr,
               float* __restrict__ tmp) {
    __shared__ float fbuf[WW];
    __shared__ float dbuf[WW];
    int i = blockIdx.x, b = blockIdx.y;
    const float* dep = depth + (long)b * HH * WW;
    const float* drow = dep + (long)i * WW;
    const int* nrow = nr + ((long)b * HH + i) * WW;
    for (int j = threadIdx.x; j < WW; j += 256) {
        float dv = drow[j];
        float f, dist;
        if (dv != 0.0f) { f = dv; dist = 0.0f; }
        else {
            int nn = nrow[j];
            int rr, cc;
            if (nn == SENT) { rr = HH - 1; cc = WW - 1; }  // clip(BIG) path
            else { rr = nn >> 11; cc = nn & 2047; }
            f = dep[(long)rr * WW + cc];
            float drr = (float)i - (float)rr, dcc = (float)j - (float)cc;
            dist = sqrtf(drr * drr + dcc * dcc);
        }
        fbuf[j] = f; dbuf[j] = dist;
    }
    __syncthreads();
    const float inv = 3.0f;  // 1920/640
    for (int ow = threadIdx.x; ow < OUT_W; ow += 256) {
        float sf = (ow + 0.5f) * inv - 0.5f;
        int i0 = (int)ceilf(sf - inv);
        float a0 = 0.f, a1 = 0.f, wsum = 0.f;
        for (int k = 0; k < 7; ++k) {
            int iw = i0 + k;
            if (iw < 0 || iw >= WW) continue;
            float wgt = 1.0f - fabsf(sf - (float)iw) / inv;
            if (wgt <= 0.0f) continue;
            a0 += wgt * fbuf[iw]; a1 += wgt * dbuf[iw]; wsum += wgt;
        }
        long o = (((long)b * 2 + 0) * HH + i) * OUT_W + ow;
        tmp[o] = a0 / wsum;
        tmp[o + (long)HH * OUT_W] = a1 / wsum;
    }
}

// ---------------- vertical resize (H 1280->427) ----------------
__global__ void vresize_k(const float* __restrict__ tmp, float* __restrict__ out) {
    int ow = blockIdx.x * blockDim.x + threadIdx.x;
    int oh = blockIdx.y, bc = blockIdx.z;  // bc = b*2 + ch
    if (ow >= OUT_W) return;
    const float inv = (float)(1280.0 / 427.0);
    float sf = (oh + 0.5f) * inv - 0.5f;
    int i0 = (int)ceilf(sf - inv);
    float acc = 0.f, wsum = 0.f;
    const float* src = tmp + (long)bc * HH * OUT_W;
    for (int k = 0; k < 7; ++k) {
        int ih = i0 + k;
        if (ih < 0 || ih >= HH) continue;
        float wgt = 1.0f - fabsf(sf - (float)ih) / inv;
        if (wgt <= 0.0f) continue;
        acc += wgt * src[(long)ih * OUT_W + ow];
        wsum += wgt;
    }
    out[((long)bc * OUT_H + oh) * OUT_W + ow] = acc / wsum;
}

extern "C" void kernel_launch(void* const* d_in, const int* in_sizes, int n_in,
                              void* d_out, int out_size, void* d_ws, size_t ws_size,
                              hipStream_t stream) {
    const float* pts  = (const float*)d_in[0];
    const float* pose = (const float*)d_in[1];
    const float* extr = (const float*)d_in[2];
    const float* intr = (const float*)d_in[3];
    int B = in_sizes[1] / 16;
    int N = in_sizes[0] / (3 * B);

    char* ws = (char*)d_ws;
    size_t imgSz = (size_t)B * HH * WW;
    float* depth = (float*)ws;                  // B*H*W f32
    int*   nearA = (int*)(ws + imgSz * 4);      // B*H*W i32
    int*   nearB = (int*)(ws + imgSz * 8);      // B*H*W i32
    float* tmp   = (float*)(ws + imgSz * 12);   // B*2*H*OUT_W f32

    hipMemsetAsync(depth, 0, imgSz * sizeof(float), stream);

    dim3 bs(256);
    scatter_k<<<dim3((N + 255) / 256, B), bs, 0, stream>>>(pts, pose, extr, intr, depth, N);

    // leading step k=1 fused with init, in LDS
    init_jfa1_k<<<dim3(WW / TSA, HH / TSA, B), 256, 0, stream>>>(depth, nearA);

    // steps 1024..1 via vectorized fused groups (global, ping-pong)
    dim3 gv((WW / 4 + 255) / 256, HH, B);
    const int steps_rest[11] = {1024, 512, 256, 128, 64, 32, 16, 8, 4, 2, 1};
    int* cur = nearA; int* nxt = nearB;
    for (int s = 0; s < 11; ++s) {
        int k = steps_rest[s];
        jfa3_k<<<gv, bs, 0, stream>>>(cur, nxt, -k, k);
        { int* t2 = cur; cur = nxt; nxt = t2; }
        jfa2_k<<<gv, bs, 0, stream>>>(cur, nxt, k);
        { int* t2 = cur; cur = nxt; nxt = t2; }
        jfa3_k<<<gv, bs, 0, stream>>>(cur, nxt, +k, k);
        { int* t2 = cur; cur = nxt; nxt = t2; }
    }

    hresize_k<<<dim3(HH, B), bs, 0, stream>>>(depth, cur, tmp);
    vresize_k<<<dim3((OUT_W + 255) / 256, OUT_H, B * 2), bs, 0, stream>>>(tmp, (float*)d_out);
}